// Round 8
// baseline (149.150 us; speedup 1.0000x reference)
//
#include <hip/hip_runtime.h>
#include <hip/hip_bf16.h>

typedef __attribute__((ext_vector_type(4))) float f32x4;
typedef __attribute__((ext_vector_type(8))) short s16x8;
typedef unsigned long long u64;

#define NB_ 4
#define N_ 4096
#define FI_ 256
#define FO_ 128
#define NROWS 16384       // NB_ * N_
#define SPLIT 4
#define JSTEP 32
#define NSTEPS ((N_ / SPLIT) / JSTEP)   // 32 steps of 32 cols

// pack two f32 -> one u32 of 2 bf16 (RNE), first arg in low half
__device__ __forceinline__ unsigned pkbf(float a, float b) {
    __hip_bfloat162 t = __float22bfloat162_rn(make_float2(a, b));
    unsigned r; __builtin_memcpy(&r, &t, 4); return r;
}

typedef __attribute__((address_space(1))) const void CGV;
typedef __attribute__((address_space(3))) void LDSV;
__device__ __forceinline__ void gload16(const void* g, void* l) {
    __builtin_amdgcn_global_load_lds((CGV*)g, (LDSV*)l, 16, 0, 0);
}

// ---------------- K0: pack W into bf16 hi/lo ----------------------------
__global__ __launch_bounds__(256) void k0_packw(
    const float* __restrict__ Ww, __hip_bfloat16* __restrict__ whi,
    __hip_bfloat16* __restrict__ wlo)
{
    int idx = blockIdx.x * 256 + threadIdx.x;           // 32768 elems
    float v = Ww[idx];
    __hip_bfloat16 hi = __float2bfloat16(v);
    whi[idx] = hi;
    wlo[idx] = __float2bfloat16(v - __bfloat162float(hi));
}

// ---------------- K1: Wh GEMM + fused epilogue --------------------------
// 1024 blocks x 16 rows. Produces WhT (bf16 [b][o][n]), srcv, dstbv, auxp.
__global__ __launch_bounds__(256) void k1_wh(
    const float* __restrict__ h, const __hip_bfloat16* __restrict__ whi,
    const __hip_bfloat16* __restrict__ wlo, const float* __restrict__ Wb,
    const float* __restrict__ aw, const float* __restrict__ ab,
    __hip_bfloat16* __restrict__ WhT, float* __restrict__ srcv,
    float* __restrict__ dstbv, unsigned* __restrict__ auxp)
{
    __shared__ float lds[16][132];
    const int tid = threadIdx.x;
    const int w = tid >> 6, l = tid & 63;
    const int lr = l & 15, g = l >> 4;
    const int r0 = blockIdx.x * 16;
    const float* hp = h + (size_t)(r0 + lr) * FI_ + g * 8;

    f32x4 acc[2] = {(f32x4)0.f, (f32x4)0.f};

    #pragma unroll
    for (int kt = 0; kt < 8; ++kt) {
        f32x4 x0 = *(const f32x4*)(hp + kt * 32);
        f32x4 x1 = *(const f32x4*)(hp + kt * 32 + 4);
        float xx[8];
        #pragma unroll
        for (int t = 0; t < 4; ++t) { xx[t] = x0[t]; xx[t + 4] = x1[t]; }
        union { s16x8 v; unsigned u[4]; } ahi, alo;
        #pragma unroll
        for (int t = 0; t < 4; ++t) {
            float a0 = xx[2 * t], a1 = xx[2 * t + 1];
            unsigned uh = pkbf(a0, a1);
            ahi.u[t] = uh;
            float h0f = __uint_as_float(uh << 16);
            float h1f = __uint_as_float(uh & 0xffff0000u);
            alo.u[t] = pkbf(a0 - h0f, a1 - h1f);
        }
        #pragma unroll
        for (int c = 0; c < 2; ++c) {
            const int o = w * 32 + c * 16 + lr;
            s16x8 bh = *(const s16x8*)(whi + (size_t)o * FI_ + kt * 32 + g * 8);
            s16x8 bl = *(const s16x8*)(wlo + (size_t)o * FI_ + kt * 32 + g * 8);
            acc[c] = __builtin_amdgcn_mfma_f32_16x16x32_bf16(ahi.v, bh, acc[c], 0, 0, 0);
            acc[c] = __builtin_amdgcn_mfma_f32_16x16x32_bf16(alo.v, bh, acc[c], 0, 0, 0);
            acc[c] = __builtin_amdgcn_mfma_f32_16x16x32_bf16(ahi.v, bl, acc[c], 0, 0, 0);
        }
    }

    #pragma unroll
    for (int c = 0; c < 2; ++c) {
        int col = w * 32 + c * 16 + lr;
        float wb = Wb[col];
        #pragma unroll
        for (int kk = 0; kk < 4; ++kk)
            lds[g * 4 + kk][col] = acc[c][kk] + wb;
    }
    __syncthreads();

    {   // WhT bf16 [b][o][n]
        const int o = tid >> 1, half = tid & 1;
        const int bb = r0 >> 12, nn = (r0 & 4095) + half * 8;
        union { s16x8 v; unsigned u[4]; } af;
        #pragma unroll
        for (int i = 0; i < 4; ++i)
            af.u[i] = pkbf(lds[half * 8 + 2 * i][o], lds[half * 8 + 2 * i + 1][o]);
        *(s16x8*)(WhT + ((size_t)bb * FO_ + o) * N_ + nn) = af.v;
    }

    {   // per-row src/dst dots + exp tables
        const int row = tid >> 4, seg = tid & 15;
        float sp = 0.f, dp = 0.f;
        #pragma unroll
        for (int i = 0; i < 8; ++i) {
            float v = lds[row][seg * 8 + i];
            sp += v * aw[seg * 8 + i];
            dp += v * aw[FO_ + seg * 8 + i];
        }
        #pragma unroll
        for (int off = 8; off >= 1; off >>= 1) {
            sp += __shfl_xor(sp, off);
            dp += __shfl_xor(dp, off);
        }
        if (seg == 0) {
            int r = r0 + row;
            srcv[r] = sp;
            float db = dp + ab[0];
            dstbv[r] = db;
            auxp[r] = pkbf(__expf(db), __expf(0.01f * db));   // lo=e1, hi=e2
        }
    }
}

// ---------------- K2b: per-batch max of dstbv ---------------------------
__global__ __launch_bounds__(256) void k2b_max(
    const float* __restrict__ dstbv, float* __restrict__ maxv)
{
    const int b = blockIdx.x;
    const int t = threadIdx.x, w = t >> 6, l = t & 63;
    float m = -3.4e38f;
    for (int i = t; i < N_; i += 256) m = fmaxf(m, dstbv[b * N_ + i]);
    #pragma unroll
    for (int off = 32; off >= 1; off >>= 1) m = fmaxf(m, __shfl_xor(m, off));
    __shared__ float red[4];
    if (l == 0) red[w] = m;
    __syncthreads();
    if (t == 0) maxv[b] = fmaxf(fmaxf(red[0], red[1]), fmaxf(red[2], red[3]));
}

// ---------------- K3: adj stream + softmax + PV, counted-vmcnt pipeline -
// grid (256, SPLIT): x = b*64 + rowblk; block = 4 waves x 16 rows, all 128 o
// B tile staged fragment-major in LDS (global_load_lds); per-step raw
// s_barrier with s_waitcnt vmcnt(4): only the 2 stage-DMAs drain, the 4
// adj/aux HBM reg-loads stay in flight across the barrier (T4).
__global__ __launch_bounds__(256, 4) void k3_gat(
    const int* __restrict__ adj, const __hip_bfloat16* __restrict__ WhT,
    const float* __restrict__ srcv, const unsigned* __restrict__ auxp,
    const float* __restrict__ maxv, float* __restrict__ pacc,
    float* __restrict__ prow)
{
    __shared__ __hip_bfloat16 bbuf[2][4096];   // 2 x 8 KB, fragment-major
    __shared__ float rsum[64];

    const int t = threadIdx.x;
    const int w = t >> 6, l = t & 63;
    const int lr = l & 15, g = l >> 4;
    const int b = blockIdx.x >> 6;
    const int rbase = (blockIdx.x & 63) * 64 + w * 16;   // wave's 16-row base
    const int myrow = rbase + lr;
    const int j0 = blockIdx.y * (N_ / SPLIT);

    float C1, C2;
    {
        float s = srcv[b * N_ + myrow];
        float eub = s + maxv[b];
        float m = fmaxf(eub, 0.01f * eub);               // >= row max of LR(e)
        C1 = __expf(s - m);
        C2 = __expf(0.01f * s - m);
    }

    const int* adjp = adj + ((size_t)(b * N_ + myrow)) * N_ + j0 + g * 8;
    const unsigned* axp = auxp + (size_t)b * N_ + j0 + g * 8;
    const short* wsrc = (const short*)WhT +
                        ((size_t)b * FO_ + w * 16 + lr) * N_ + j0 + g * 8;

    f32x4 acc[8];
    #pragma unroll
    for (int ot = 0; ot < 8; ++ot) acc[ot] = (f32x4)0.f;
    float rs = 0.f;

    auto stage = [&](int bi, int s) {
        const int jb = s * JSTEP;
        gload16(wsrc + jb,                      &bbuf[bi][(0 * 256 + w * 64) * 8]);
        gload16(wsrc + (size_t)(64) * N_ + jb,  &bbuf[bi][(1 * 256 + w * 64) * 8]);
    };

    // ---- prologue: stage(0) first (ordered), then reg loads ----
    int4 a0c, a1c; uint4 xc0, xc1;
    stage(0, 0);
    __builtin_amdgcn_sched_barrier(0);
    a0c = *(const int4*)(adjp);
    a1c = *(const int4*)(adjp + 4);
    xc0 = *(const uint4*)(axp);
    xc1 = *(const uint4*)(axp + 4);
    __builtin_amdgcn_sched_barrier(0);
    asm volatile("s_waitcnt vmcnt(4)" ::: "memory");     // stage(0) done, regs fly
    __builtin_amdgcn_sched_barrier(0);
    __builtin_amdgcn_s_barrier();
    __builtin_amdgcn_sched_barrier(0);
    int cur = 0;

    for (int s = 0; s < NSTEPS; ++s) {
        int4 a0n = {0,0,0,0}, a1n = {0,0,0,0};
        uint4 xn0 = {0,0,0,0}, xn1 = {0,0,0,0};
        const bool more = (s + 1 < NSTEPS);
        if (more) {                                      // issue-early: DMA first
            stage(cur ^ 1, s + 1);
            __builtin_amdgcn_sched_barrier(0);
            const int jn = (s + 1) * JSTEP;
            a0n = *(const int4*)(adjp + jn);
            a1n = *(const int4*)(adjp + jn + 4);
            xn0 = *(const uint4*)(axp + jn);
            xn1 = *(const uint4*)(axp + jn + 4);
            __builtin_amdgcn_sched_barrier(0);
        }

        // decode current regs (compiler waits only the OLD loads, leaves new 6)
        const unsigned ax[8] = {xc0.x, xc0.y, xc0.z, xc0.w, xc1.x, xc1.y, xc1.z, xc1.w};
        const int av[8] = {a0c.x, a0c.y, a0c.z, a0c.w, a1c.x, a1c.y, a1c.z, a1c.w};
        float p[8];
        #pragma unroll
        for (int e = 0; e < 8; ++e) {
            float e1f = __uint_as_float(ax[e] << 16);
            float e2f = __uint_as_float(ax[e] & 0xffff0000u);
            float v = fmaxf(e1f * C1, e2f * C2);         // exact LR softmax p
            p[e] = (av[e] > 0) ? v : 0.f;
            rs += p[e];
        }
        union { s16x8 v; unsigned u[4]; } af;
        af.u[0] = pkbf(p[0], p[1]); af.u[1] = pkbf(p[2], p[3]);
        af.u[2] = pkbf(p[4], p[5]); af.u[3] = pkbf(p[6], p[7]);

        __builtin_amdgcn_s_setprio(1);
        #pragma unroll
        for (int ot = 0; ot < 8; ++ot) {
            s16x8 Bf = *(const s16x8*)&bbuf[cur][(ot * 64 + l) * 8];
            acc[ot] = __builtin_amdgcn_mfma_f32_16x16x32_bf16(af.v, Bf, acc[ot], 0, 0, 0);
        }
        __builtin_amdgcn_s_setprio(0);

        if (more) {
            // only the 2 stage-DMAs must retire; adj/aux regs stay outstanding
            __builtin_amdgcn_sched_barrier(0);
            asm volatile("s_waitcnt vmcnt(4)" ::: "memory");
            __builtin_amdgcn_sched_barrier(0);
            __builtin_amdgcn_s_barrier();
            __builtin_amdgcn_sched_barrier(0);
        }
        a0c = a0n; a1c = a1n; xc0 = xn0; xc1 = xn1;
        cur ^= 1;
    }

    // row-sum: reduce over g-groups, park in LDS for C-layout epilogue
    rs += __shfl_xor(rs, 16);
    rs += __shfl_xor(rs, 32);
    if (g == 0) rsum[w * 16 + lr] = rs;
    __syncthreads();

    const size_t sb = (size_t)blockIdx.y * ((size_t)NROWS * FO_);
    #pragma unroll
    for (int kk = 0; kk < 4; ++kk) {
        int grow = b * N_ + rbase + g * 4 + kk;
        float* pp = pacc + sb + (size_t)grow * FO_ + lr;
        #pragma unroll
        for (int ot = 0; ot < 8; ++ot)
            pp[ot * 16] = acc[ot][kk];
        if (lr == 0)
            prow[blockIdx.y * NROWS + grow] = rsum[w * 16 + g * 4 + kk];
    }
}

// ---------------- K4: combine split partials + normalize ----------------
__global__ __launch_bounds__(256) void k4_comb(
    const float* __restrict__ pacc, const float* __restrict__ prow,
    float* __restrict__ out)
{
    const int idx = blockIdx.x * 256 + threadIdx.x;      // 2,097,152
    const int grow = idx >> 7;
    float s = 0.f, rs = 0.f;
    #pragma unroll
    for (int si = 0; si < SPLIT; ++si) {
        s  += pacc[(size_t)si * ((size_t)NROWS * FO_) + idx];
        rs += prow[si * NROWS + grow];
    }
    out[idx] = s / rs;
}

extern "C" void kernel_launch(void* const* d_in, const int* in_sizes, int n_in,
                              void* d_out, int out_size, void* d_ws, size_t ws_size,
                              hipStream_t stream)
{
    const float* h  = (const float*)d_in[0];
    const int* adj  = (const int*)d_in[1];
    const float* Ww = (const float*)d_in[2];
    const float* Wb = (const float*)d_in[3];
    const float* aw = (const float*)d_in[4];
    const float* ab = (const float*)d_in[5];
    float* out = (float*)d_out;

    char* wsb = (char*)d_ws;                             // ws_size ~1 GB
    float* pacc          = (float*)wsb;                               // 32 MB
    __hip_bfloat16* WhT  = (__hip_bfloat16*)(wsb + 33554432u);        // 4 MB
    char* aux            = wsb + 37748736u;
    float* srcv          = (float*)(aux);                             // 64 KB
    float* dstbv         = (float*)(aux + (64u << 10));               // 64 KB
    unsigned* auxp       = (unsigned*)(aux + (128u << 10));           // 64 KB
    __hip_bfloat16* whi  = (__hip_bfloat16*)(aux + (192u << 10));     // 64 KB
    __hip_bfloat16* wlo  = (__hip_bfloat16*)(aux + (256u << 10));     // 64 KB
    float* maxv          = (float*)(aux + (320u << 10));              // 16 B
    float* prow          = (float*)(aux + (384u << 10));              // 256 KB

    k0_packw<<<128, 256, 0, stream>>>(Ww, whi, wlo);
    k1_wh<<<1024, 256, 0, stream>>>(h, whi, wlo, Wb, aw, ab, WhT, srcv, dstbv, auxp);
    k2b_max<<<4, 256, 0, stream>>>(dstbv, maxv);
    dim3 g3(NB_ * 64, SPLIT);
    k3_gat<<<g3, 256, 0, stream>>>(adj, WhT, srcv, auxp, maxv, pacc, prow);
    k4_comb<<<8192, 256, 0, stream>>>(pacc, prow, out);
}

// Round 9
// 130.848 us; speedup vs baseline: 1.1399x; 1.1399x over previous
//
#include <hip/hip_runtime.h>
#include <hip/hip_bf16.h>

typedef __attribute__((ext_vector_type(4))) float f32x4;
typedef __attribute__((ext_vector_type(8))) short s16x8;
typedef unsigned long long u64;

#define NB_ 4
#define N_ 4096
#define FI_ 256
#define FO_ 128
#define NROWS 16384       // NB_ * N_
#define SPLIT 4
#define NSTEPS ((N_ / SPLIT) / 32)   // 32 steps of 32 cols

// pack two f32 -> one u32 of 2 bf16 (RNE), first arg in low half
__device__ __forceinline__ unsigned pkbf(float a, float b) {
    __hip_bfloat162 t = __float22bfloat162_rn(make_float2(a, b));
    unsigned r; __builtin_memcpy(&r, &t, 4); return r;
}

typedef __attribute__((address_space(1))) const void CGV;
typedef __attribute__((address_space(3))) void LDSV;
__device__ __forceinline__ void gload16(const void* g, void* l) {
    __builtin_amdgcn_global_load_lds((CGV*)g, (LDSV*)l, 16, 0, 0);
}

// ---------------- K0: pack W into bf16 hi/lo ----------------------------
__global__ __launch_bounds__(256) void k0_packw(
    const float* __restrict__ Ww, __hip_bfloat16* __restrict__ whi,
    __hip_bfloat16* __restrict__ wlo)
{
    int idx = blockIdx.x * 256 + threadIdx.x;           // 32768 elems
    float v = Ww[idx];
    __hip_bfloat16 hi = __float2bfloat16(v);
    whi[idx] = hi;
    wlo[idx] = __float2bfloat16(v - __bfloat162float(hi));
}

// ---------------- K1: Wh GEMM + fused epilogue --------------------------
// 1024 blocks x 16 rows(j). Emits WhTf = fragment-major bf16 tiles:
// WhTf[b][jblk][frag o>>4][lane (o&15)+16*(jin>>3)][elem jin&7]
__global__ __launch_bounds__(256) void k1_wh(
    const float* __restrict__ h, const __hip_bfloat16* __restrict__ whi,
    const __hip_bfloat16* __restrict__ wlo, const float* __restrict__ Wb,
    const float* __restrict__ aw, const float* __restrict__ ab,
    short* __restrict__ WhTf, float* __restrict__ srcv,
    float* __restrict__ dstbv, unsigned* __restrict__ auxp)
{
    __shared__ float lds[16][132];
    const int tid = threadIdx.x;
    const int w = tid >> 6, l = tid & 63;
    const int lr = l & 15, g = l >> 4;
    const int r0 = blockIdx.x * 16;
    const float* hp = h + (size_t)(r0 + lr) * FI_ + g * 8;

    f32x4 acc[2] = {(f32x4)0.f, (f32x4)0.f};

    #pragma unroll
    for (int kt = 0; kt < 8; ++kt) {
        f32x4 x0 = *(const f32x4*)(hp + kt * 32);
        f32x4 x1 = *(const f32x4*)(hp + kt * 32 + 4);
        float xx[8];
        #pragma unroll
        for (int t = 0; t < 4; ++t) { xx[t] = x0[t]; xx[t + 4] = x1[t]; }
        union { s16x8 v; unsigned u[4]; } ahi, alo;
        #pragma unroll
        for (int t = 0; t < 4; ++t) {
            float a0 = xx[2 * t], a1 = xx[2 * t + 1];
            unsigned uh = pkbf(a0, a1);
            ahi.u[t] = uh;
            float h0f = __uint_as_float(uh << 16);
            float h1f = __uint_as_float(uh & 0xffff0000u);
            alo.u[t] = pkbf(a0 - h0f, a1 - h1f);
        }
        #pragma unroll
        for (int c = 0; c < 2; ++c) {
            const int o = w * 32 + c * 16 + lr;
            s16x8 bh = *(const s16x8*)(whi + (size_t)o * FI_ + kt * 32 + g * 8);
            s16x8 bl = *(const s16x8*)(wlo + (size_t)o * FI_ + kt * 32 + g * 8);
            acc[c] = __builtin_amdgcn_mfma_f32_16x16x32_bf16(ahi.v, bh, acc[c], 0, 0, 0);
            acc[c] = __builtin_amdgcn_mfma_f32_16x16x32_bf16(alo.v, bh, acc[c], 0, 0, 0);
            acc[c] = __builtin_amdgcn_mfma_f32_16x16x32_bf16(ahi.v, bl, acc[c], 0, 0, 0);
        }
    }

    #pragma unroll
    for (int c = 0; c < 2; ++c) {
        int col = w * 32 + c * 16 + lr;
        float wb = Wb[col];
        #pragma unroll
        for (int kk = 0; kk < 4; ++kk)
            lds[g * 4 + kk][col] = acc[c][kk] + wb;   // local j x o
    }
    __syncthreads();

    {   // WhTf fragment-major store: thread -> (o = t>>1, joct = t&1), 16 B
        const int o = tid >> 1, joct = tid & 1;
        const int jblk = (r0 & 4095) >> 5;
        const int bb = r0 >> 12;
        const int lb = ((r0 >> 3) & 3) + joct;        // jin>>3
        union { s16x8 v; unsigned u[4]; } af;
        #pragma unroll
        for (int q = 0; q < 4; ++q)
            af.u[q] = pkbf(lds[joct * 8 + 2 * q][o], lds[joct * 8 + 2 * q + 1][o]);
        short* dst = WhTf + (((size_t)bb * 128 + jblk) * 8 + (o >> 4)) * 512
                          + ((o & 15) + 16 * lb) * 8;
        *(s16x8*)dst = af.v;
    }

    {   // per-row src/dst dots + exp tables
        const int row = tid >> 4, seg = tid & 15;
        float sp = 0.f, dp = 0.f;
        #pragma unroll
        for (int i = 0; i < 8; ++i) {
            float v = lds[row][seg * 8 + i];
            sp += v * aw[seg * 8 + i];
            dp += v * aw[FO_ + seg * 8 + i];
        }
        #pragma unroll
        for (int off = 8; off >= 1; off >>= 1) {
            sp += __shfl_xor(sp, off);
            dp += __shfl_xor(dp, off);
        }
        if (seg == 0) {
            int r = r0 + row;
            srcv[r] = sp;
            float db = dp + ab[0];
            dstbv[r] = db;
            auxp[r] = pkbf(__expf(db), __expf(0.01f * db));   // lo=e1, hi=e2
        }
    }
}

// ---------------- K2b: per-batch max of dstbv ---------------------------
__global__ __launch_bounds__(256) void k2b_max(
    const float* __restrict__ dstbv, float* __restrict__ maxv)
{
    const int b = blockIdx.x;
    const int t = threadIdx.x, w = t >> 6, l = t & 63;
    float m = -3.4e38f;
    for (int i = t; i < N_; i += 256) m = fmaxf(m, dstbv[b * N_ + i]);
    #pragma unroll
    for (int off = 32; off >= 1; off >>= 1) m = fmaxf(m, __shfl_xor(m, off));
    __shared__ float red[4];
    if (l == 0) red[w] = m;
    __syncthreads();
    if (t == 0) maxv[b] = fmaxf(fmaxf(red[0], red[1]), fmaxf(red[2], red[3]));
}

// ---------------- K3: wave-contiguous adj/WhTf staging + softmax + PV ---
// grid (256, SPLIT): x = b*64 + rowblk(64 rows). 4 waves:
//   wave w: rh=w&1 (rows rh*32 + rt*16), oh=w>>1 (o-half, 64 cols)
// adj tile 64x32 staged to LDS with in-row lane walk + XOR-16B swizzle;
// B tile 8 KB staged fully contiguous from fragment-major WhTf.
__global__ __launch_bounds__(256, 4) void k3_gat(
    const int* __restrict__ adj, const short* __restrict__ WhTf,
    const float* __restrict__ srcv, const unsigned* __restrict__ auxp,
    const float* __restrict__ maxv, float* __restrict__ pacc,
    float* __restrict__ prow)
{
    __shared__ int adjb[2][64][32];            // 2 x 8 KB, 16B-chunk swizzled
    __shared__ __hip_bfloat16 whb[2][4096];    // 2 x 8 KB, fragment-major
    __shared__ float rsum[64];

    const int t = threadIdx.x;
    const int w = t >> 6, l = t & 63;
    const int lr = l & 15, g = l >> 4;
    const int rh = w & 1, oh = w >> 1;
    const int b = blockIdx.x >> 6;
    const int rblk = (blockIdx.x & 63) * 64;              // block row base
    const int bN = b * N_;
    const int j0 = blockIdx.y * (N_ / SPLIT);

    float C1[2], C2[2];
    {
        const float mdb = maxv[b];
        #pragma unroll
        for (int rt = 0; rt < 2; ++rt) {
            int r = rblk + rh * 32 + rt * 16 + lr;
            float s = srcv[bN + r];
            float eub = s + mdb;
            float m = fmaxf(eub, 0.01f * eub);            // >= row max of LR(e)
            C1[rt] = __expf(s - m);
            C2[rt] = __expf(0.01f * s - m);
        }
    }

    const unsigned* axp = auxp + (size_t)bN + j0 + g * 8;
    const short* whsrc = WhTf + ((size_t)b * 128 + (j0 >> 5)) * 4096;

    f32x4 acc[2][4];
    #pragma unroll
    for (int rt = 0; rt < 2; ++rt)
        #pragma unroll
        for (int ot = 0; ot < 4; ++ot) acc[rt][ot] = (f32x4)0.f;
    float rs0 = 0.f, rs1 = 0.f;

    // adj stage: slot = r*8+c; LDS chunk c holds source chunk c^(r&7)
    auto stage_adj = [&](int bi, int s) {
        const int jb = j0 + s * 32;
        #pragma unroll
        for (int i = 0; i < 2; ++i) {
            int r = (t >> 3) + i * 32;                    // 0..63
            int c = t & 7;
            const int* src = adj + (size_t)(bN + rblk + r) * N_ + jb
                                 + ((c ^ (r & 7)) << 2);
            gload16(src, &adjb[bi][0][0] + (size_t)(i * 256 + w * 64) * 4);
        }
    };
    // WhTf stage: fully contiguous 8 KB
    auto stage_wh = [&](int bi, int s) {
        const short* src = whsrc + (size_t)s * 4096;
        #pragma unroll
        for (int i = 0; i < 2; ++i)
            gload16(src + (size_t)(i * 256 + t) * 8,
                    &whb[bi][0] + (size_t)(i * 256 + w * 64) * 8);
    };

    uint4 xc0, xc1;
    stage_adj(0, 0);
    stage_wh(0, 0);
    xc0 = *(const uint4*)(axp);
    xc1 = *(const uint4*)(axp + 4);
    __syncthreads();
    int cur = 0;

    for (int s = 0; s < NSTEPS; ++s) {
        uint4 xn0 = {0, 0, 0, 0}, xn1 = {0, 0, 0, 0};
        const bool more = (s + 1 < NSTEPS);
        if (more) {
            stage_adj(cur ^ 1, s + 1);
            stage_wh(cur ^ 1, s + 1);
            const int jn = (s + 1) * 32;
            xn0 = *(const uint4*)(axp + jn);
            xn1 = *(const uint4*)(axp + jn + 4);
        }

        // shared unpack of e1/e2 (same j for both rowsets)
        const unsigned ax[8] = {xc0.x, xc0.y, xc0.z, xc0.w,
                                xc1.x, xc1.y, xc1.z, xc1.w};
        float e1f[8], e2f[8];
        #pragma unroll
        for (int e = 0; e < 8; ++e) {
            e1f[e] = __uint_as_float(ax[e] << 16);
            e2f[e] = __uint_as_float(ax[e] & 0xffff0000u);
        }
        // B fragments (shared by both rowsets)
        s16x8 Bf[4];
        #pragma unroll
        for (int ot = 0; ot < 4; ++ot)
            Bf[ot] = *(const s16x8*)&whb[cur][(size_t)((oh * 4 + ot) * 64 + l) * 8];

        #pragma unroll
        for (int rt = 0; rt < 2; ++rt) {
            const int R = rh * 32 + rt * 16 + lr;
            const int4 a0 = *(const int4*)&adjb[cur][R][((2 * g) ^ (lr & 7)) << 2];
            const int4 a1 = *(const int4*)&adjb[cur][R][((2 * g + 1) ^ (lr & 7)) << 2];
            const int av[8] = {a0.x, a0.y, a0.z, a0.w, a1.x, a1.y, a1.z, a1.w};
            float p[8];
            #pragma unroll
            for (int e = 0; e < 8; ++e) {
                float v = fmaxf(e1f[e] * C1[rt], e2f[e] * C2[rt]);
                p[e] = (av[e] > 0) ? v : 0.f;
                if (rt == 0) rs0 += p[e]; else rs1 += p[e];
            }
            union { s16x8 v; unsigned u[4]; } af;
            af.u[0] = pkbf(p[0], p[1]); af.u[1] = pkbf(p[2], p[3]);
            af.u[2] = pkbf(p[4], p[5]); af.u[3] = pkbf(p[6], p[7]);
            #pragma unroll
            for (int ot = 0; ot < 4; ++ot)
                acc[rt][ot] = __builtin_amdgcn_mfma_f32_16x16x32_bf16(
                    af.v, Bf[ot], acc[rt][ot], 0, 0, 0);
        }

        __syncthreads();    // next-step DMA done; all waves done with [cur]
        xc0 = xn0; xc1 = xn1;
        cur ^= 1;
    }

    // row-sums: reduce over g-groups (j-octets), park per block-row
    rs0 += __shfl_xor(rs0, 16); rs0 += __shfl_xor(rs0, 32);
    rs1 += __shfl_xor(rs1, 16); rs1 += __shfl_xor(rs1, 32);
    if (oh == 0 && l < 16) {
        rsum[rh * 32 + l] = rs0;
        rsum[rh * 32 + 16 + l] = rs1;
    }
    __syncthreads();

    const size_t sb = (size_t)blockIdx.y * ((size_t)NROWS * FO_);
    #pragma unroll
    for (int rt = 0; rt < 2; ++rt) {
        #pragma unroll
        for (int kk = 0; kk < 4; ++kk) {
            int rloc = rh * 32 + rt * 16 + g * 4 + kk;
            int grow = bN + rblk + rloc;
            float* pp = pacc + sb + (size_t)grow * FO_ + oh * 64 + lr;
            #pragma unroll
            for (int ot = 0; ot < 4; ++ot)
                pp[ot * 16] = acc[rt][ot][kk];
            if (oh == 0 && lr == 0)
                prow[blockIdx.y * NROWS + grow] = rsum[rloc];
        }
    }
}

// ---------------- K4: combine split partials + normalize ----------------
__global__ __launch_bounds__(256) void k4_comb(
    const float* __restrict__ pacc, const float* __restrict__ prow,
    float* __restrict__ out)
{
    const int idx = blockIdx.x * 256 + threadIdx.x;      // 2,097,152
    const int grow = idx >> 7;
    float s = 0.f, rs = 0.f;
    #pragma unroll
    for (int si = 0; si < SPLIT; ++si) {
        s  += pacc[(size_t)si * ((size_t)NROWS * FO_) + idx];
        rs += prow[si * NROWS + grow];
    }
    out[idx] = s / rs;
}

extern "C" void kernel_launch(void* const* d_in, const int* in_sizes, int n_in,
                              void* d_out, int out_size, void* d_ws, size_t ws_size,
                              hipStream_t stream)
{
    const float* h  = (const float*)d_in[0];
    const int* adj  = (const int*)d_in[1];
    const float* Ww = (const float*)d_in[2];
    const float* Wb = (const float*)d_in[3];
    const float* aw = (const float*)d_in[4];
    const float* ab = (const float*)d_in[5];
    float* out = (float*)d_out;

    char* wsb = (char*)d_ws;                             // ws_size ~1 GB
    float* pacc          = (float*)wsb;                               // 32 MB
    short* WhTf          = (short*)(wsb + 33554432u);                 // 4 MB
    char* aux            = wsb + 37748736u;
    float* srcv          = (float*)(aux);                             // 64 KB
    float* dstbv         = (float*)(aux + (64u << 10));               // 64 KB
    unsigned* auxp       = (unsigned*)(aux + (128u << 10));           // 64 KB
    __hip_bfloat16* whi  = (__hip_bfloat16*)(aux + (192u << 10));     // 64 KB
    __hip_bfloat16* wlo  = (__hip_bfloat16*)(aux + (256u << 10));     // 64 KB
    float* maxv          = (float*)(aux + (320u << 10));              // 16 B
    float* prow          = (float*)(aux + (384u << 10));              // 256 KB

    k0_packw<<<128, 256, 0, stream>>>(Ww, whi, wlo);
    k1_wh<<<1024, 256, 0, stream>>>(h, whi, wlo, Wb, aw, ab, WhTf, srcv, dstbv, auxp);
    k2b_max<<<4, 256, 0, stream>>>(dstbv, maxv);
    dim3 g3(NB_ * 64, SPLIT);
    k3_gat<<<g3, 256, 0, stream>>>(adj, WhTf, srcv, auxp, maxv, pacc, prow);
    k4_comb<<<8192, 256, 0, stream>>>(pacc, prow, out);
}